// Round 2
// baseline (1045.035 us; speedup 1.0000x reference)
//
#include <hip/hip_runtime.h>
#include <math.h>

#define NNODES 50000
#define INF    256
#define OUTF   64
#define NEDGES 800000
#define NBINS  782            // ceil(50000/64), 64 nodes per bin

#define KB  32                // GEMM K tile
#define ATS 68                // A_t LDS stride

// ---------------------------------------------------------------------------
// GEMM + activation epilogue (unchanged this round; MFMA conversion later).
// ---------------------------------------------------------------------------
__global__ __launch_bounds__(256, 2) void gemm_act(
    const float* __restrict__ feat,
    const float* __restrict__ Wm,
    const float* __restrict__ Ws,
    float* __restrict__ u,
    float* __restrict__ v,
    int n_nodes)
{
    __shared__ __align__(16) float A_t[KB][ATS];
    __shared__ __align__(16) float Bm[KB][OUTF];
    __shared__ __align__(16) float Bs[KB][OUTF];

    const int tid = threadIdx.x;
    const int tx  = tid & 15;
    const int ty  = tid >> 4;
    const int m0  = blockIdx.x * 64;

    float accm[4][4] = {};
    float accs[4][4] = {};

    for (int kb = 0; kb < INF; kb += KB) {
        #pragma unroll
        for (int r = 0; r < 2; ++r) {
            int idx = tid + r * 256;
            int row = idx >> 3;
            int q   = idx & 7;
            int m   = m0 + row;
            float4 val = make_float4(0.f, 0.f, 0.f, 0.f);
            if (m < n_nodes)
                val = *(const float4*)&feat[(size_t)m * INF + kb + q * 4];
            A_t[q * 4 + 0][row] = val.x;
            A_t[q * 4 + 1][row] = val.y;
            A_t[q * 4 + 2][row] = val.z;
            A_t[q * 4 + 3][row] = val.w;
        }
        #pragma unroll
        for (int r = 0; r < 2; ++r) {
            int idx = tid + r * 256;
            int k   = idx >> 4;
            int q   = idx & 15;
            *(float4*)&Bm[k][q * 4] = *(const float4*)&Wm[(size_t)(kb + k) * OUTF + q * 4];
            *(float4*)&Bs[k][q * 4] = *(const float4*)&Ws[(size_t)(kb + k) * OUTF + q * 4];
        }
        __syncthreads();

        #pragma unroll
        for (int k = 0; k < KB; ++k) {
            float4 a4  = *(const float4*)&A_t[k][ty * 4];
            float4 bm4 = *(const float4*)&Bm[k][tx * 4];
            float4 bs4 = *(const float4*)&Bs[k][tx * 4];
            float av[4]  = {a4.x, a4.y, a4.z, a4.w};
            float bmv[4] = {bm4.x, bm4.y, bm4.z, bm4.w};
            float bsv[4] = {bs4.x, bs4.y, bs4.z, bs4.w};
            #pragma unroll
            for (int i = 0; i < 4; ++i)
                #pragma unroll
                for (int j = 0; j < 4; ++j) {
                    accm[i][j] = fmaf(av[i], bmv[j], accm[i][j]);
                    accs[i][j] = fmaf(av[i], bsv[j], accs[i][j]);
                }
        }
        __syncthreads();
    }

    #pragma unroll
    for (int i = 0; i < 4; ++i) {
        int m = m0 + ty * 4 + i;
        if (m >= n_nodes) continue;
        float4 uo, vo;
        float* up = (float*)&uo;
        float* vp = (float*)&vo;
        #pragma unroll
        for (int j = 0; j < 4; ++j) {
            float cm  = accm[i][j];
            float miu = cm > 0.f ? cm : expm1f(cm);
            float cs  = accs[i][j];
            float sig = cs > 0.f ? cs : 0.f;
            float att = __expf(-sig);
            up[j] = miu * att;
            vp[j] = sig * att * att;
        }
        *(float4*)&u[(size_t)m * OUTF + tx * 4] = uo;
        *(float4*)&v[(size_t)m * OUTF + tx * 4] = vo;
    }
}

// ---------------------------------------------------------------------------
// K1: histogram of dst bins (bin = dst >> 6). LDS-aggregated.
// ---------------------------------------------------------------------------
__global__ __launch_bounds__(256) void hist_kernel(
    const int* __restrict__ edst, int* __restrict__ hist)
{
    __shared__ int lh[NBINS];
    for (int i = threadIdx.x; i < NBINS; i += 256) lh[i] = 0;
    __syncthreads();

    int stride = gridDim.x * 256;
    for (int e = blockIdx.x * 256 + threadIdx.x; e < NEDGES; e += stride)
        atomicAdd(&lh[edst[e] >> 6], 1);
    __syncthreads();

    for (int i = threadIdx.x; i < NBINS; i += 256) {
        int c = lh[i];
        if (c) atomicAdd(&hist[i], c);
    }
}

// ---------------------------------------------------------------------------
// K2: exclusive prefix scan over 782 bins (single block, Hillis-Steele).
// ---------------------------------------------------------------------------
__global__ __launch_bounds__(1024) void scan_kernel(
    const int* __restrict__ hist, int* __restrict__ binStart,
    int* __restrict__ binCursor)
{
    __shared__ int buf[1024];
    int t = threadIdx.x;
    buf[t] = (t < NBINS) ? hist[t] : 0;
    __syncthreads();
    for (int off = 1; off < 1024; off <<= 1) {
        int val = (t >= off) ? buf[t - off] : 0;
        __syncthreads();
        buf[t] += val;
        __syncthreads();
    }
    if (t < NBINS) {
        int excl = (t == 0) ? 0 : buf[t - 1];
        binStart[t]  = excl;
        binCursor[t] = excl;
    }
    if (t == NBINS) binStart[NBINS] = buf[NBINS - 1];
}

// ---------------------------------------------------------------------------
// K3: place edge ids into bin segments.
// ---------------------------------------------------------------------------
__global__ __launch_bounds__(256) void place_kernel(
    const int* __restrict__ edst, int* __restrict__ binCursor,
    int* __restrict__ eid)
{
    int stride = gridDim.x * 256;
    for (int e = blockIdx.x * 256 + threadIdx.x; e < NEDGES; e += stride) {
        int pos = atomicAdd(&binCursor[edst[e] >> 6], 1);
        eid[pos] = e;
    }
}

// ---------------------------------------------------------------------------
// K4: per-bin accumulation in LDS, coalesced write. NO global atomics.
// One block per bin; 4 waves process edges round-robin; lane = feature.
// Writes every output element -> no d_out memset needed.
// ---------------------------------------------------------------------------
__global__ __launch_bounds__(256, 2) void accum_kernel(
    const int* __restrict__ eid,
    const int* __restrict__ binStart,
    const int* __restrict__ esrc,
    const int* __restrict__ edst,
    const float* __restrict__ a1,
    const float* __restrict__ a2,
    const float* __restrict__ u,
    const float* __restrict__ v,
    float* __restrict__ outm,
    float* __restrict__ outs)
{
    __shared__ float accM[64 * 64];   // [node_in_bin][feat] 16 KB
    __shared__ float accS[64 * 64];   // 16 KB

    const int bin  = blockIdx.x;
    const int tid  = threadIdx.x;
    const int wv   = tid >> 6;
    const int lane = tid & 63;

    for (int i = tid; i < 64 * 64; i += 256) { accM[i] = 0.f; accS[i] = 0.f; }
    __syncthreads();

    const int start = binStart[bin];
    const int end   = binStart[bin + 1];

    for (int i = start + wv; i < end; i += 4) {
        int   e  = eid[i];
        int   s  = esrc[e];
        int   d  = edst[e];
        float w1 = a1[e];
        float w2 = a2[e];
        float uv = u[(size_t)s * OUTF + lane];
        float vv = v[(size_t)s * OUTF + lane];
        int   r  = (d - (bin << 6)) << 6;
        atomicAdd(&accM[r + lane], w1 * uv);   // ds_add_f32
        atomicAdd(&accS[r + lane], w2 * vv);
    }
    __syncthreads();

    for (int t = tid; t < 64 * 64; t += 256) {
        int node = (bin << 6) + (t >> 6);
        if (node < NNODES) {
            outm[(size_t)node * OUTF + (t & 63)] = accM[t];
            outs[(size_t)node * OUTF + (t & 63)] = accS[t];
        }
    }
}

extern "C" void kernel_launch(void* const* d_in, const int* in_sizes, int n_in,
                              void* d_out, int out_size, void* d_ws, size_t ws_size,
                              hipStream_t stream)
{
    const float* feat = (const float*)d_in[0];
    const int*   esrc = (const int*)d_in[1];
    const int*   edst = (const int*)d_in[2];
    const float* a1   = (const float*)d_in[3];
    const float* a2   = (const float*)d_in[4];
    const float* Wm   = (const float*)d_in[5];
    const float* Ws   = (const float*)d_in[6];

    float* outm = (float*)d_out;
    float* outs = outm + (size_t)NNODES * OUTF;

    // workspace layout
    char* ws = (char*)d_ws;
    float* u         = (float*)ws;                        ws += (size_t)NNODES * OUTF * 4;  // 12.8 MB
    float* v         = (float*)ws;                        ws += (size_t)NNODES * OUTF * 4;  // 12.8 MB
    int*   eid       = (int*)ws;                          ws += (size_t)NEDGES * 4;         // 3.2 MB
    int*   hist      = (int*)ws;                          ws += (NBINS + 2) * 4;
    int*   binStart  = (int*)ws;                          ws += (NBINS + 2) * 4;
    int*   binCursor = (int*)ws;

    // zero only the histogram (scan overwrites binStart/binCursor)
    hipMemsetAsync(hist, 0, (NBINS + 2) * sizeof(int), stream);

    gemm_act<<<dim3((NNODES + 63) / 64), dim3(256), 0, stream>>>(
        feat, Wm, Ws, u, v, NNODES);

    hist_kernel<<<dim3(256), dim3(256), 0, stream>>>(edst, hist);
    scan_kernel<<<dim3(1), dim3(1024), 0, stream>>>(hist, binStart, binCursor);
    place_kernel<<<dim3(256), dim3(256), 0, stream>>>(edst, binCursor, eid);
    accum_kernel<<<dim3(NBINS), dim3(256), 0, stream>>>(
        eid, binStart, esrc, edst, a1, a2, u, v, outm, outs);
}

// Round 3
// 414.215 us; speedup vs baseline: 2.5229x; 2.5229x over previous
//
#include <hip/hip_runtime.h>
#include <math.h>

#define NNODES 50000
#define INF    256
#define OUTF   64
#define NEDGES 800000

#define KB  32                // GEMM K tile
#define ATS 68                // A_t LDS stride

// ---------------------------------------------------------------------------
// GEMM + activation epilogue (unchanged; MFMA conversion next round).
// ---------------------------------------------------------------------------
__global__ __launch_bounds__(256, 2) void gemm_act(
    const float* __restrict__ feat,
    const float* __restrict__ Wm,
    const float* __restrict__ Ws,
    float* __restrict__ u,
    float* __restrict__ v,
    int n_nodes)
{
    __shared__ __align__(16) float A_t[KB][ATS];
    __shared__ __align__(16) float Bm[KB][OUTF];
    __shared__ __align__(16) float Bs[KB][OUTF];

    const int tid = threadIdx.x;
    const int tx  = tid & 15;
    const int ty  = tid >> 4;
    const int m0  = blockIdx.x * 64;

    float accm[4][4] = {};
    float accs[4][4] = {};

    for (int kb = 0; kb < INF; kb += KB) {
        #pragma unroll
        for (int r = 0; r < 2; ++r) {
            int idx = tid + r * 256;
            int row = idx >> 3;
            int q   = idx & 7;
            int m   = m0 + row;
            float4 val = make_float4(0.f, 0.f, 0.f, 0.f);
            if (m < n_nodes)
                val = *(const float4*)&feat[(size_t)m * INF + kb + q * 4];
            A_t[q * 4 + 0][row] = val.x;
            A_t[q * 4 + 1][row] = val.y;
            A_t[q * 4 + 2][row] = val.z;
            A_t[q * 4 + 3][row] = val.w;
        }
        #pragma unroll
        for (int r = 0; r < 2; ++r) {
            int idx = tid + r * 256;
            int k   = idx >> 4;
            int q   = idx & 15;
            *(float4*)&Bm[k][q * 4] = *(const float4*)&Wm[(size_t)(kb + k) * OUTF + q * 4];
            *(float4*)&Bs[k][q * 4] = *(const float4*)&Ws[(size_t)(kb + k) * OUTF + q * 4];
        }
        __syncthreads();

        #pragma unroll
        for (int k = 0; k < KB; ++k) {
            float4 a4  = *(const float4*)&A_t[k][ty * 4];
            float4 bm4 = *(const float4*)&Bm[k][tx * 4];
            float4 bs4 = *(const float4*)&Bs[k][tx * 4];
            float av[4]  = {a4.x, a4.y, a4.z, a4.w};
            float bmv[4] = {bm4.x, bm4.y, bm4.z, bm4.w};
            float bsv[4] = {bs4.x, bs4.y, bs4.z, bs4.w};
            #pragma unroll
            for (int i = 0; i < 4; ++i)
                #pragma unroll
                for (int j = 0; j < 4; ++j) {
                    accm[i][j] = fmaf(av[i], bmv[j], accm[i][j]);
                    accs[i][j] = fmaf(av[i], bsv[j], accs[i][j]);
                }
        }
        __syncthreads();
    }

    #pragma unroll
    for (int i = 0; i < 4; ++i) {
        int m = m0 + ty * 4 + i;
        if (m >= n_nodes) continue;
        float4 uo, vo;
        float* up = (float*)&uo;
        float* vp = (float*)&vo;
        #pragma unroll
        for (int j = 0; j < 4; ++j) {
            float cm  = accm[i][j];
            float miu = cm > 0.f ? cm : expm1f(cm);
            float cs  = accs[i][j];
            float sig = cs > 0.f ? cs : 0.f;
            float att = __expf(-sig);
            up[j] = miu * att;
            vp[j] = sig * att * att;
        }
        *(float4*)&u[(size_t)m * OUTF + tx * 4] = uo;
        *(float4*)&v[(size_t)m * OUTF + tx * 4] = vo;
    }
}

// ---------------------------------------------------------------------------
// K1: per-NODE histogram of dst. 50000 counters, global atomics (~16 avg
// contention, uniform — no hotspot).
// ---------------------------------------------------------------------------
__global__ __launch_bounds__(256) void hist_kernel(
    const int* __restrict__ edst, int* __restrict__ cnt)
{
    int e = blockIdx.x * 256 + threadIdx.x;
    if (e < NEDGES) atomicAdd(&cnt[edst[e]], 1);
}

// ---------------------------------------------------------------------------
// K2: exclusive scan over 50000 node counts. Single block, 1024 threads,
// 49 nodes/thread sequential + Hillis-Steele over 1024 partials.
// Writes start[] and cursor[].
// ---------------------------------------------------------------------------
#define SCAN_PER 49
__global__ __launch_bounds__(1024) void scan_kernel(
    const int* __restrict__ cnt, int* __restrict__ start,
    int* __restrict__ cursor)
{
    __shared__ int buf[1024];
    const int t    = threadIdx.x;
    const int base = t * SCAN_PER;

    int loc[SCAN_PER];
    int sum = 0;
    #pragma unroll
    for (int j = 0; j < SCAN_PER; ++j) {
        int n = base + j;
        loc[j] = (n < NNODES) ? cnt[n] : 0;
        sum += loc[j];
    }
    buf[t] = sum;
    __syncthreads();
    #pragma unroll
    for (int off = 1; off < 1024; off <<= 1) {
        int val = (t >= off) ? buf[t - off] : 0;
        __syncthreads();
        buf[t] += val;
        __syncthreads();
    }
    int run = (t == 0) ? 0 : buf[t - 1];   // exclusive offset for this thread
    #pragma unroll
    for (int j = 0; j < SCAN_PER; ++j) {
        int n = base + j;
        if (n < NNODES) {
            start[n]  = run;
            cursor[n] = run;
            run += loc[j];
        }
    }
    if (t == 1023) start[NNODES] = NEDGES;
}

// ---------------------------------------------------------------------------
// K3: place edge ids into per-node segments.
// ---------------------------------------------------------------------------
__global__ __launch_bounds__(256) void place_kernel(
    const int* __restrict__ edst, int* __restrict__ cursor,
    int* __restrict__ eid)
{
    int e = blockIdx.x * 256 + threadIdx.x;
    if (e < NEDGES) {
        int pos = atomicAdd(&cursor[edst[e]], 1);
        eid[pos] = e;
    }
}

// ---------------------------------------------------------------------------
// K4: one wave per dst node; lane = feature; accumulate in registers.
// 4-edge unroll -> 8 independent 256B gathers in flight per wave.
// No atomics, no LDS. Writes every output element (no d_out memset needed).
// ---------------------------------------------------------------------------
__global__ __launch_bounds__(256) void gather_accum(
    const int* __restrict__ eid,
    const int* __restrict__ start,
    const int* __restrict__ esrc,
    const float* __restrict__ a1,
    const float* __restrict__ a2,
    const float* __restrict__ u,
    const float* __restrict__ v,
    float* __restrict__ outm,
    float* __restrict__ outs)
{
    const int n    = blockIdx.x * 4 + (threadIdx.x >> 6);
    const int lane = threadIdx.x & 63;
    if (n >= NNODES) return;

    const int beg = start[n];
    const int end = start[n + 1];

    float am = 0.f, as = 0.f;
    int i = beg;
    for (; i + 4 <= end; i += 4) {
        int e0 = eid[i + 0], e1 = eid[i + 1], e2 = eid[i + 2], e3 = eid[i + 3];
        int s0 = esrc[e0], s1 = esrc[e1], s2 = esrc[e2], s3 = esrc[e3];
        float u0 = u[(size_t)s0 * OUTF + lane];
        float u1 = u[(size_t)s1 * OUTF + lane];
        float u2 = u[(size_t)s2 * OUTF + lane];
        float u3 = u[(size_t)s3 * OUTF + lane];
        float v0 = v[(size_t)s0 * OUTF + lane];
        float v1 = v[(size_t)s1 * OUTF + lane];
        float v2 = v[(size_t)s2 * OUTF + lane];
        float v3 = v[(size_t)s3 * OUTF + lane];
        float w10 = a1[e0], w11 = a1[e1], w12 = a1[e2], w13 = a1[e3];
        float w20 = a2[e0], w21 = a2[e1], w22 = a2[e2], w23 = a2[e3];
        am = fmaf(w10, u0, am); am = fmaf(w11, u1, am);
        am = fmaf(w12, u2, am); am = fmaf(w13, u3, am);
        as = fmaf(w20, v0, as); as = fmaf(w21, v1, as);
        as = fmaf(w22, v2, as); as = fmaf(w23, v3, as);
    }
    for (; i < end; ++i) {
        int e = eid[i];
        int s = esrc[e];
        am = fmaf(a1[e], u[(size_t)s * OUTF + lane], am);
        as = fmaf(a2[e], v[(size_t)s * OUTF + lane], as);
    }

    outm[(size_t)n * OUTF + lane] = am;
    outs[(size_t)n * OUTF + lane] = as;
}

extern "C" void kernel_launch(void* const* d_in, const int* in_sizes, int n_in,
                              void* d_out, int out_size, void* d_ws, size_t ws_size,
                              hipStream_t stream)
{
    const float* feat = (const float*)d_in[0];
    const int*   esrc = (const int*)d_in[1];
    const int*   edst = (const int*)d_in[2];
    const float* a1   = (const float*)d_in[3];
    const float* a2   = (const float*)d_in[4];
    const float* Wm   = (const float*)d_in[5];
    const float* Ws   = (const float*)d_in[6];

    float* outm = (float*)d_out;
    float* outs = outm + (size_t)NNODES * OUTF;

    // workspace layout (~29.8 MB)
    char* ws = (char*)d_ws;
    float* u      = (float*)ws;  ws += (size_t)NNODES * OUTF * 4;   // 12.8 MB
    float* v      = (float*)ws;  ws += (size_t)NNODES * OUTF * 4;   // 12.8 MB
    int*   eid    = (int*)ws;    ws += (size_t)NEDGES * 4;          // 3.2 MB
    int*   cnt    = (int*)ws;    ws += (size_t)NNODES * 4;          // 200 KB
    int*   start  = (int*)ws;    ws += (size_t)(NNODES + 1) * 4;    // 200 KB
    int*   cursor = (int*)ws;

    hipMemsetAsync(cnt, 0, (size_t)NNODES * sizeof(int), stream);

    gemm_act<<<dim3((NNODES + 63) / 64), dim3(256), 0, stream>>>(
        feat, Wm, Ws, u, v, NNODES);

    hist_kernel<<<dim3((NEDGES + 255) / 256), dim3(256), 0, stream>>>(edst, cnt);
    scan_kernel<<<dim3(1), dim3(1024), 0, stream>>>(cnt, start, cursor);
    place_kernel<<<dim3((NEDGES + 255) / 256), dim3(256), 0, stream>>>(edst, cursor, eid);
    gather_accum<<<dim3((NNODES + 3) / 4), dim3(256), 0, stream>>>(
        eid, start, esrc, a1, a2, u, v, outm, outs);
}

// Round 4
// 347.416 us; speedup vs baseline: 3.0080x; 1.1923x over previous
//
#include <hip/hip_runtime.h>
#include <math.h>

#define NNODES 50000
#define INF    256
#define OUTF   64
#define NEDGES 800000

typedef __attribute__((ext_vector_type(8))) short bf16x8;
typedef __attribute__((ext_vector_type(4))) float f32x4;

__device__ __forceinline__ unsigned short f2bf(float x) {
    unsigned int b = __float_as_uint(x);
    unsigned int r = b + 0x7FFF + ((b >> 16) & 1);   // RNE
    return (unsigned short)(r >> 16);
}

// ---------------------------------------------------------------------------
// K0: transpose+convert weights to bf16:  BtG[n][k], n 0..127 (Wm cols 0-63,
// Ws cols 64-127), k 0..255. Tiny (32k elems).
// ---------------------------------------------------------------------------
__global__ __launch_bounds__(256) void convert_B(
    const float* __restrict__ Wm, const float* __restrict__ Ws,
    unsigned short* __restrict__ BtG)
{
    int n = blockIdx.x;          // 0..127
    int k = threadIdx.x;         // 0..255
    float val = (n < 64) ? Wm[(size_t)k * OUTF + n]
                         : Ws[(size_t)k * OUTF + (n - 64)];
    BtG[(size_t)n * INF + k] = f2bf(val);
}

// ---------------------------------------------------------------------------
// K-GEMM: bf16 MFMA fused dual-GEMM + activation epilogue.
// Block: 256 thr = 4 waves; tile M=64 (16 rows/wave), N=128, K-tile 32.
// Output: packed uv[node][feat] = (bf16 u | bf16 v << 16).
// Frag layouts (m89/m120-verified): A[m=lane&15][k=quad*8+j],
// B[n=lane&15][k=quad*8+j], C col=lane&15 row=quad*4+reg.
// ---------------------------------------------------------------------------
#define LDA 40   // padded k-stride (bf16 elems): 80B rows -> 2-way banks (free)
__global__ __launch_bounds__(256, 2) void gemm_mfma(
    const float* __restrict__ feat,
    const unsigned short* __restrict__ BtG,
    unsigned int* __restrict__ uv,
    int n_nodes)
{
    __shared__ __align__(16) unsigned short As[64 * LDA];    // 5.1 KB
    __shared__ __align__(16) unsigned short Bs[128 * LDA];   // 10.2 KB

    const int tid  = threadIdx.x;
    const int w    = tid >> 6;
    const int lane = tid & 63;
    const int quad = lane >> 4;
    const int col  = lane & 15;
    const int m0   = blockIdx.x * 64;

    f32x4 acc[8];
    #pragma unroll
    for (int c = 0; c < 8; ++c) acc[c] = (f32x4){0.f, 0.f, 0.f, 0.f};

    for (int kb = 0; kb < INF; kb += 32) {
        // ---- A tile: 64 rows x 32 k fp32 -> bf16 LDS ----
        #pragma unroll
        for (int r = 0; r < 2; ++r) {
            int i   = tid + r * 256;       // float4 idx over [64][8]
            int row = i >> 3;
            int q4  = i & 7;
            int m   = m0 + row;
            float4 val = make_float4(0.f, 0.f, 0.f, 0.f);
            if (m < n_nodes)
                val = *(const float4*)&feat[(size_t)m * INF + kb + q4 * 4];
            unsigned short p0 = f2bf(val.x), p1 = f2bf(val.y);
            unsigned short p2 = f2bf(val.z), p3 = f2bf(val.w);
            unsigned int lo = (unsigned int)p0 | ((unsigned int)p1 << 16);
            unsigned int hi = (unsigned int)p2 | ((unsigned int)p3 << 16);
            *(uint2*)&As[row * LDA + q4 * 4] = make_uint2(lo, hi);
        }
        // ---- B tile: 128 n x 32 k bf16, already n-major in global ----
        #pragma unroll
        for (int r = 0; r < 2; ++r) {
            int i = tid + r * 256;         // 16B-chunk idx over [128][4]
            int n = i >> 2;
            int q = i & 3;
            uint4 val = *(const uint4*)&BtG[(size_t)n * INF + kb + q * 8];
            *(uint4*)&Bs[n * LDA + q * 8] = val;
        }
        __syncthreads();

        bf16x8 af = *(const bf16x8*)&As[(16 * w + col) * LDA + quad * 8];
        #pragma unroll
        for (int c = 0; c < 8; ++c) {
            bf16x8 bf = *(const bf16x8*)&Bs[(16 * c + col) * LDA + quad * 8];
            acc[c] = __builtin_amdgcn_mfma_f32_16x16x32_bf16(af, bf, acc[c], 0, 0, 0);
        }
        __syncthreads();
    }

    // ---- epilogue: activations, pack bf16 u|v ----
    const int mbase = m0 + 16 * w + quad * 4;
    #pragma unroll
    for (int c = 0; c < 4; ++c) {
        int f = 16 * c + col;
        #pragma unroll
        for (int r = 0; r < 4; ++r) {
            int m = mbase + r;
            if (m >= n_nodes) continue;
            float cm  = acc[c][r];
            float cs  = acc[c + 4][r];
            float miu = cm > 0.f ? cm : expm1f(cm);
            float sig = cs > 0.f ? cs : 0.f;
            float att = __expf(-sig);
            float uu  = miu * att;
            float vv  = sig * att * att;
            unsigned int p = (unsigned int)f2bf(uu) | ((unsigned int)f2bf(vv) << 16);
            uv[(size_t)m * OUTF + f] = p;
        }
    }
}

// ---------------------------------------------------------------------------
// K1: per-node histogram of dst.
// ---------------------------------------------------------------------------
__global__ __launch_bounds__(256) void hist_kernel(
    const int* __restrict__ edst, int* __restrict__ cnt)
{
    int e = blockIdx.x * 256 + threadIdx.x;
    if (e < NEDGES) atomicAdd(&cnt[edst[e]], 1);
}

// ---------------------------------------------------------------------------
// K2: exclusive scan over 50000 counts (single block).
// ---------------------------------------------------------------------------
#define SCAN_PER 49
__global__ __launch_bounds__(1024) void scan_kernel(
    const int* __restrict__ cnt, int* __restrict__ start,
    int* __restrict__ cursor)
{
    __shared__ int buf[1024];
    const int t    = threadIdx.x;
    const int base = t * SCAN_PER;

    int loc[SCAN_PER];
    int sum = 0;
    #pragma unroll
    for (int j = 0; j < SCAN_PER; ++j) {
        int n = base + j;
        loc[j] = (n < NNODES) ? cnt[n] : 0;
        sum += loc[j];
    }
    buf[t] = sum;
    __syncthreads();
    #pragma unroll
    for (int off = 1; off < 1024; off <<= 1) {
        int val = (t >= off) ? buf[t - off] : 0;
        __syncthreads();
        buf[t] += val;
        __syncthreads();
    }
    int run = (t == 0) ? 0 : buf[t - 1];
    #pragma unroll
    for (int j = 0; j < SCAN_PER; ++j) {
        int n = base + j;
        if (n < NNODES) {
            start[n]  = run;
            cursor[n] = run;
            run += loc[j];
        }
    }
    if (t == 1023) start[NNODES] = NEDGES;
}

// ---------------------------------------------------------------------------
// K3: place edge ids into per-node segments.
// ---------------------------------------------------------------------------
__global__ __launch_bounds__(256) void place_kernel(
    const int* __restrict__ edst, int* __restrict__ cursor,
    int* __restrict__ eid)
{
    int e = blockIdx.x * 256 + threadIdx.x;
    if (e < NEDGES) {
        int pos = atomicAdd(&cursor[edst[e]], 1);
        eid[pos] = e;
    }
}

// ---------------------------------------------------------------------------
// K4: one wave per dst node; lane = feature; packed-bf16 uv gather (256B/edge).
// ---------------------------------------------------------------------------
__global__ __launch_bounds__(256) void gather_accum(
    const int* __restrict__ eid,
    const int* __restrict__ start,
    const int* __restrict__ esrc,
    const float* __restrict__ a1,
    const float* __restrict__ a2,
    const unsigned int* __restrict__ uv,
    float* __restrict__ outm,
    float* __restrict__ outs)
{
    const int n    = blockIdx.x * 4 + (threadIdx.x >> 6);
    const int lane = threadIdx.x & 63;
    if (n >= NNODES) return;

    const int beg = start[n];
    const int end = start[n + 1];

    float am = 0.f, as = 0.f;
    int i = beg;
    for (; i + 4 <= end; i += 4) {
        int e0 = eid[i + 0], e1 = eid[i + 1], e2 = eid[i + 2], e3 = eid[i + 3];
        int s0 = esrc[e0], s1 = esrc[e1], s2 = esrc[e2], s3 = esrc[e3];
        unsigned int p0 = uv[(size_t)s0 * OUTF + lane];
        unsigned int p1 = uv[(size_t)s1 * OUTF + lane];
        unsigned int p2 = uv[(size_t)s2 * OUTF + lane];
        unsigned int p3 = uv[(size_t)s3 * OUTF + lane];
        float w10 = a1[e0], w11 = a1[e1], w12 = a1[e2], w13 = a1[e3];
        float w20 = a2[e0], w21 = a2[e1], w22 = a2[e2], w23 = a2[e3];
        am = fmaf(w10, __uint_as_float(p0 << 16), am);
        am = fmaf(w11, __uint_as_float(p1 << 16), am);
        am = fmaf(w12, __uint_as_float(p2 << 16), am);
        am = fmaf(w13, __uint_as_float(p3 << 16), am);
        as = fmaf(w20, __uint_as_float(p0 & 0xFFFF0000u), as);
        as = fmaf(w21, __uint_as_float(p1 & 0xFFFF0000u), as);
        as = fmaf(w22, __uint_as_float(p2 & 0xFFFF0000u), as);
        as = fmaf(w23, __uint_as_float(p3 & 0xFFFF0000u), as);
    }
    for (; i < end; ++i) {
        int e = eid[i];
        int s = esrc[e];
        unsigned int p = uv[(size_t)s * OUTF + lane];
        am = fmaf(a1[e], __uint_as_float(p << 16), am);
        as = fmaf(a2[e], __uint_as_float(p & 0xFFFF0000u), as);
    }

    outm[(size_t)n * OUTF + lane] = am;
    outs[(size_t)n * OUTF + lane] = as;
}

extern "C" void kernel_launch(void* const* d_in, const int* in_sizes, int n_in,
                              void* d_out, int out_size, void* d_ws, size_t ws_size,
                              hipStream_t stream)
{
    const float* feat = (const float*)d_in[0];
    const int*   esrc = (const int*)d_in[1];
    const int*   edst = (const int*)d_in[2];
    const float* a1   = (const float*)d_in[3];
    const float* a2   = (const float*)d_in[4];
    const float* Wm   = (const float*)d_in[5];
    const float* Ws   = (const float*)d_in[6];

    float* outm = (float*)d_out;
    float* outs = outm + (size_t)NNODES * OUTF;

    // workspace layout (~17 MB)
    char* ws = (char*)d_ws;
    unsigned int*   uv  = (unsigned int*)ws;   ws += (size_t)NNODES * OUTF * 4;  // 12.8 MB
    unsigned short* BtG = (unsigned short*)ws; ws += (size_t)128 * INF * 2;      // 64 KB
    int* eid    = (int*)ws;  ws += (size_t)NEDGES * 4;                            // 3.2 MB
    int* cnt    = (int*)ws;  ws += (size_t)NNODES * 4;
    int* start  = (int*)ws;  ws += (size_t)(NNODES + 1) * 4;
    int* cursor = (int*)ws;

    hipMemsetAsync(cnt, 0, (size_t)NNODES * sizeof(int), stream);

    convert_B<<<dim3(128), dim3(256), 0, stream>>>(Wm, Ws, BtG);

    gemm_mfma<<<dim3((NNODES + 63) / 64), dim3(256), 0, stream>>>(
        feat, BtG, uv, NNODES);

    hist_kernel<<<dim3((NEDGES + 255) / 256), dim3(256), 0, stream>>>(edst, cnt);
    scan_kernel<<<dim3(1), dim3(1024), 0, stream>>>(cnt, start, cursor);
    place_kernel<<<dim3((NEDGES + 255) / 256), dim3(256), 0, stream>>>(edst, cursor, eid);
    gather_accum<<<dim3((NNODES + 3) / 4), dim3(256), 0, stream>>>(
        eid, start, esrc, a1, a2, uv, outm, outs);
}

// Round 5
// 276.774 us; speedup vs baseline: 3.7758x; 1.2552x over previous
//
#include <hip/hip_runtime.h>
#include <math.h>

#define NNODES 50000
#define INF    256
#define OUTF   64
#define NEDGES 800000
#define NCHUNK 196            // ceil(50000/256)

typedef __attribute__((ext_vector_type(8))) short bf16x8;
typedef __attribute__((ext_vector_type(4))) float f32x4;

__device__ __forceinline__ unsigned short f2bf(float x) {
    unsigned int b = __float_as_uint(x);
    unsigned int r = b + 0x7FFF + ((b >> 16) & 1);   // RNE
    return (unsigned short)(r >> 16);
}

// ---------------------------------------------------------------------------
// K0: transpose+convert weights to bf16:  BtG[n][k], n 0..127 (Wm cols 0-63,
// Ws cols 64-127), k 0..255.
// ---------------------------------------------------------------------------
__global__ __launch_bounds__(256) void convert_B(
    const float* __restrict__ Wm, const float* __restrict__ Ws,
    unsigned short* __restrict__ BtG)
{
    int n = blockIdx.x;          // 0..127
    int k = threadIdx.x;         // 0..255
    float val = (n < 64) ? Wm[(size_t)k * OUTF + n]
                         : Ws[(size_t)k * OUTF + (n - 64)];
    BtG[(size_t)n * INF + k] = f2bf(val);
}

// ---------------------------------------------------------------------------
// K-GEMM: bf16 MFMA fused dual-GEMM + activation epilogue.
// ---------------------------------------------------------------------------
#define LDA 40   // padded k-stride (bf16 elems)
__global__ __launch_bounds__(256, 2) void gemm_mfma(
    const float* __restrict__ feat,
    const unsigned short* __restrict__ BtG,
    unsigned int* __restrict__ uv,
    int n_nodes)
{
    __shared__ __align__(16) unsigned short As[64 * LDA];
    __shared__ __align__(16) unsigned short Bs[128 * LDA];

    const int tid  = threadIdx.x;
    const int w    = tid >> 6;
    const int lane = tid & 63;
    const int quad = lane >> 4;
    const int col  = lane & 15;
    const int m0   = blockIdx.x * 64;

    f32x4 acc[8];
    #pragma unroll
    for (int c = 0; c < 8; ++c) acc[c] = (f32x4){0.f, 0.f, 0.f, 0.f};

    for (int kb = 0; kb < INF; kb += 32) {
        #pragma unroll
        for (int r = 0; r < 2; ++r) {
            int i   = tid + r * 256;
            int row = i >> 3;
            int q4  = i & 7;
            int m   = m0 + row;
            float4 val = make_float4(0.f, 0.f, 0.f, 0.f);
            if (m < n_nodes)
                val = *(const float4*)&feat[(size_t)m * INF + kb + q4 * 4];
            unsigned short p0 = f2bf(val.x), p1 = f2bf(val.y);
            unsigned short p2 = f2bf(val.z), p3 = f2bf(val.w);
            unsigned int lo = (unsigned int)p0 | ((unsigned int)p1 << 16);
            unsigned int hi = (unsigned int)p2 | ((unsigned int)p3 << 16);
            *(uint2*)&As[row * LDA + q4 * 4] = make_uint2(lo, hi);
        }
        #pragma unroll
        for (int r = 0; r < 2; ++r) {
            int i = tid + r * 256;
            int n = i >> 2;
            int q = i & 3;
            uint4 val = *(const uint4*)&BtG[(size_t)n * INF + kb + q * 8];
            *(uint4*)&Bs[n * LDA + q * 8] = val;
        }
        __syncthreads();

        bf16x8 af = *(const bf16x8*)&As[(16 * w + col) * LDA + quad * 8];
        #pragma unroll
        for (int c = 0; c < 8; ++c) {
            bf16x8 bf = *(const bf16x8*)&Bs[(16 * c + col) * LDA + quad * 8];
            acc[c] = __builtin_amdgcn_mfma_f32_16x16x32_bf16(af, bf, acc[c], 0, 0, 0);
        }
        __syncthreads();
    }

    const int mbase = m0 + 16 * w + quad * 4;
    #pragma unroll
    for (int c = 0; c < 4; ++c) {
        int f = 16 * c + col;
        #pragma unroll
        for (int r = 0; r < 4; ++r) {
            int m = mbase + r;
            if (m >= n_nodes) continue;
            float cm  = acc[c][r];
            float cs  = acc[c + 4][r];
            float miu = cm > 0.f ? cm : expm1f(cm);
            float sig = cs > 0.f ? cs : 0.f;
            float att = __expf(-sig);
            float uu  = miu * att;
            float vv  = sig * att * att;
            unsigned int p = (unsigned int)f2bf(uu) | ((unsigned int)f2bf(vv) << 16);
            uv[(size_t)m * OUTF + f] = p;
        }
    }
}

// ---------------------------------------------------------------------------
// K1: per-node histogram of dst.
// ---------------------------------------------------------------------------
__global__ __launch_bounds__(256) void hist_kernel(
    const int* __restrict__ edst, int* __restrict__ cnt)
{
    int e = blockIdx.x * 256 + threadIdx.x;
    if (e < NEDGES) atomicAdd(&cnt[edst[e]], 1);
}

// ---------------------------------------------------------------------------
// K2a: per-chunk sums of cnt (196 chunks x 256 nodes). Coalesced.
// ---------------------------------------------------------------------------
__global__ __launch_bounds__(256) void chunk_sum(
    const int* __restrict__ cnt, int* __restrict__ chunkSum)
{
    __shared__ int buf[256];
    const int t   = threadIdx.x;
    const int idx = blockIdx.x * 256 + t;
    buf[t] = (idx < NNODES) ? cnt[idx] : 0;
    __syncthreads();
    #pragma unroll
    for (int off = 128; off > 0; off >>= 1) {
        if (t < off) buf[t] += buf[t + off];
        __syncthreads();
    }
    if (t == 0) chunkSum[blockIdx.x] = buf[0];
}

// ---------------------------------------------------------------------------
// K2b: per-chunk exclusive scan + write start/cursor. Each block derives its
// chunk offset by reducing chunkSum[0..b) in LDS (196 values — cheap).
// ---------------------------------------------------------------------------
__global__ __launch_bounds__(256) void scan_write(
    const int* __restrict__ cnt, const int* __restrict__ chunkSum,
    int* __restrict__ start, int* __restrict__ cursor)
{
    __shared__ int pre[256];   // chunk sums masked to t < b
    __shared__ int buf[256];   // local scan
    const int t   = threadIdx.x;
    const int b   = blockIdx.x;
    const int idx = b * 256 + t;

    pre[t] = (t < NCHUNK && t < b) ? chunkSum[t] : 0;
    int val = (idx < NNODES) ? cnt[idx] : 0;
    buf[t] = val;
    __syncthreads();

    // reduce pre[] -> chunk offset
    #pragma unroll
    for (int off = 128; off > 0; off >>= 1) {
        if (t < off) pre[t] += pre[t + off];
        __syncthreads();
    }
    const int chunkOff = pre[0];

    // Hillis-Steele inclusive scan of buf[]
    #pragma unroll
    for (int off = 1; off < 256; off <<= 1) {
        int x = (t >= off) ? buf[t - off] : 0;
        __syncthreads();
        buf[t] += x;
        __syncthreads();
    }
    if (idx < NNODES) {
        int excl = chunkOff + buf[t] - val;
        start[idx]  = excl;
        cursor[idx] = excl;
    }
    if (b == NCHUNK - 1 && t == 255) start[NNODES] = NEDGES;
}

// ---------------------------------------------------------------------------
// K3: place edge ids into per-node segments.
// ---------------------------------------------------------------------------
__global__ __launch_bounds__(256) void place_kernel(
    const int* __restrict__ edst, int* __restrict__ cursor,
    int* __restrict__ eid)
{
    int e = blockIdx.x * 256 + threadIdx.x;
    if (e < NEDGES) {
        int pos = atomicAdd(&cursor[edst[e]], 1);
        eid[pos] = e;
    }
}

// ---------------------------------------------------------------------------
// K4: one wave per dst node; lane = feature; packed-bf16 uv gather.
// ---------------------------------------------------------------------------
__global__ __launch_bounds__(256) void gather_accum(
    const int* __restrict__ eid,
    const int* __restrict__ start,
    const int* __restrict__ esrc,
    const float* __restrict__ a1,
    const float* __restrict__ a2,
    const unsigned int* __restrict__ uv,
    float* __restrict__ outm,
    float* __restrict__ outs)
{
    const int n    = blockIdx.x * 4 + (threadIdx.x >> 6);
    const int lane = threadIdx.x & 63;
    if (n >= NNODES) return;

    const int beg = start[n];
    const int end = start[n + 1];

    float am = 0.f, as = 0.f;
    int i = beg;
    for (; i + 4 <= end; i += 4) {
        int e0 = eid[i + 0], e1 = eid[i + 1], e2 = eid[i + 2], e3 = eid[i + 3];
        int s0 = esrc[e0], s1 = esrc[e1], s2 = esrc[e2], s3 = esrc[e3];
        unsigned int p0 = uv[(size_t)s0 * OUTF + lane];
        unsigned int p1 = uv[(size_t)s1 * OUTF + lane];
        unsigned int p2 = uv[(size_t)s2 * OUTF + lane];
        unsigned int p3 = uv[(size_t)s3 * OUTF + lane];
        float w10 = a1[e0], w11 = a1[e1], w12 = a1[e2], w13 = a1[e3];
        float w20 = a2[e0], w21 = a2[e1], w22 = a2[e2], w23 = a2[e3];
        am = fmaf(w10, __uint_as_float(p0 << 16), am);
        am = fmaf(w11, __uint_as_float(p1 << 16), am);
        am = fmaf(w12, __uint_as_float(p2 << 16), am);
        am = fmaf(w13, __uint_as_float(p3 << 16), am);
        as = fmaf(w20, __uint_as_float(p0 & 0xFFFF0000u), as);
        as = fmaf(w21, __uint_as_float(p1 & 0xFFFF0000u), as);
        as = fmaf(w22, __uint_as_float(p2 & 0xFFFF0000u), as);
        as = fmaf(w23, __uint_as_float(p3 & 0xFFFF0000u), as);
    }
    for (; i < end; ++i) {
        int e = eid[i];
        int s = esrc[e];
        unsigned int p = uv[(size_t)s * OUTF + lane];
        am = fmaf(a1[e], __uint_as_float(p << 16), am);
        as = fmaf(a2[e], __uint_as_float(p & 0xFFFF0000u), as);
    }

    outm[(size_t)n * OUTF + lane] = am;
    outs[(size_t)n * OUTF + lane] = as;
}

extern "C" void kernel_launch(void* const* d_in, const int* in_sizes, int n_in,
                              void* d_out, int out_size, void* d_ws, size_t ws_size,
                              hipStream_t stream)
{
    const float* feat = (const float*)d_in[0];
    const int*   esrc = (const int*)d_in[1];
    const int*   edst = (const int*)d_in[2];
    const float* a1   = (const float*)d_in[3];
    const float* a2   = (const float*)d_in[4];
    const float* Wm   = (const float*)d_in[5];
    const float* Ws   = (const float*)d_in[6];

    float* outm = (float*)d_out;
    float* outs = outm + (size_t)NNODES * OUTF;

    // workspace layout (~17 MB)
    char* ws = (char*)d_ws;
    unsigned int*   uv  = (unsigned int*)ws;   ws += (size_t)NNODES * OUTF * 4;  // 12.8 MB
    unsigned short* BtG = (unsigned short*)ws; ws += (size_t)128 * INF * 2;      // 64 KB
    int* eid      = (int*)ws;  ws += (size_t)NEDGES * 4;                          // 3.2 MB
    int* cnt      = (int*)ws;  ws += (size_t)NNODES * 4;
    int* start    = (int*)ws;  ws += (size_t)(NNODES + 1) * 4;
    int* cursor   = (int*)ws;  ws += (size_t)NNODES * 4;
    int* chunkSum = (int*)ws;

    hipMemsetAsync(cnt, 0, (size_t)NNODES * sizeof(int), stream);

    convert_B<<<dim3(128), dim3(256), 0, stream>>>(Wm, Ws, BtG);

    gemm_mfma<<<dim3((NNODES + 63) / 64), dim3(256), 0, stream>>>(
        feat, BtG, uv, NNODES);

    hist_kernel<<<dim3((NEDGES + 255) / 256), dim3(256), 0, stream>>>(edst, cnt);
    chunk_sum<<<dim3(NCHUNK), dim3(256), 0, stream>>>(cnt, chunkSum);
    scan_write<<<dim3(NCHUNK), dim3(256), 0, stream>>>(cnt, chunkSum, start, cursor);
    place_kernel<<<dim3((NEDGES + 255) / 256), dim3(256), 0, stream>>>(edst, cursor, eid);
    gather_accum<<<dim3((NNODES + 3) / 4), dim3(256), 0, stream>>>(
        eid, start, esrc, a1, a2, uv, outm, outs);
}

// Round 6
// 262.455 us; speedup vs baseline: 3.9818x; 1.0546x over previous
//
#include <hip/hip_runtime.h>
#include <math.h>

#define NNODES 50000
#define INF    256
#define OUTF   64
#define NEDGES 800000
#define NCHUNK 196            // ceil(50000/256)
#define CVTBLK 128            // blocks doing weight conversion in fused K1

typedef __attribute__((ext_vector_type(8))) short bf16x8;
typedef __attribute__((ext_vector_type(4))) float f32x4;

__device__ __forceinline__ unsigned short f2bf(float x) {
    unsigned int b = __float_as_uint(x);
    unsigned int r = b + 0x7FFF + ((b >> 16) & 1);   // RNE
    return (unsigned short)(r >> 16);
}

// ---------------------------------------------------------------------------
// K1 (fused): blocks 0..127 transpose+convert weights to bf16 BtG[n][k];
// blocks 128.. do the per-node dst histogram.
// ---------------------------------------------------------------------------
__global__ __launch_bounds__(256) void convert_hist(
    const float* __restrict__ Wm, const float* __restrict__ Ws,
    unsigned short* __restrict__ BtG,
    const int* __restrict__ edst, int* __restrict__ cnt)
{
    if (blockIdx.x < CVTBLK) {
        int n = blockIdx.x;          // 0..127
        int k = threadIdx.x;         // 0..255
        float val = (n < 64) ? Wm[(size_t)k * OUTF + n]
                             : Ws[(size_t)k * OUTF + (n - 64)];
        BtG[(size_t)n * INF + k] = f2bf(val);
    } else {
        int e = (blockIdx.x - CVTBLK) * 256 + threadIdx.x;
        if (e < NEDGES) atomicAdd(&cnt[edst[e]], 1);
    }
}

// ---------------------------------------------------------------------------
// K-GEMM: bf16 MFMA fused dual-GEMM + activation epilogue.
// ---------------------------------------------------------------------------
#define LDA 40   // padded k-stride (bf16 elems)
__global__ __launch_bounds__(256, 2) void gemm_mfma(
    const float* __restrict__ feat,
    const unsigned short* __restrict__ BtG,
    unsigned int* __restrict__ uv,
    int n_nodes)
{
    __shared__ __align__(16) unsigned short As[64 * LDA];
    __shared__ __align__(16) unsigned short Bs[128 * LDA];

    const int tid  = threadIdx.x;
    const int w    = tid >> 6;
    const int lane = tid & 63;
    const int quad = lane >> 4;
    const int col  = lane & 15;
    const int m0   = blockIdx.x * 64;

    f32x4 acc[8];
    #pragma unroll
    for (int c = 0; c < 8; ++c) acc[c] = (f32x4){0.f, 0.f, 0.f, 0.f};

    for (int kb = 0; kb < INF; kb += 32) {
        #pragma unroll
        for (int r = 0; r < 2; ++r) {
            int i   = tid + r * 256;
            int row = i >> 3;
            int q4  = i & 7;
            int m   = m0 + row;
            float4 val = make_float4(0.f, 0.f, 0.f, 0.f);
            if (m < n_nodes)
                val = *(const float4*)&feat[(size_t)m * INF + kb + q4 * 4];
            unsigned short p0 = f2bf(val.x), p1 = f2bf(val.y);
            unsigned short p2 = f2bf(val.z), p3 = f2bf(val.w);
            unsigned int lo = (unsigned int)p0 | ((unsigned int)p1 << 16);
            unsigned int hi = (unsigned int)p2 | ((unsigned int)p3 << 16);
            *(uint2*)&As[row * LDA + q4 * 4] = make_uint2(lo, hi);
        }
        #pragma unroll
        for (int r = 0; r < 2; ++r) {
            int i = tid + r * 256;
            int n = i >> 2;
            int q = i & 3;
            uint4 val = *(const uint4*)&BtG[(size_t)n * INF + kb + q * 8];
            *(uint4*)&Bs[n * LDA + q * 8] = val;
        }
        __syncthreads();

        bf16x8 af = *(const bf16x8*)&As[(16 * w + col) * LDA + quad * 8];
        #pragma unroll
        for (int c = 0; c < 8; ++c) {
            bf16x8 bf = *(const bf16x8*)&Bs[(16 * c + col) * LDA + quad * 8];
            acc[c] = __builtin_amdgcn_mfma_f32_16x16x32_bf16(af, bf, acc[c], 0, 0, 0);
        }
        __syncthreads();
    }

    const int mbase = m0 + 16 * w + quad * 4;
    #pragma unroll
    for (int c = 0; c < 4; ++c) {
        int f = 16 * c + col;
        #pragma unroll
        for (int r = 0; r < 4; ++r) {
            int m = mbase + r;
            if (m >= n_nodes) continue;
            float cm  = acc[c][r];
            float cs  = acc[c + 4][r];
            float miu = cm > 0.f ? cm : expm1f(cm);
            float sig = cs > 0.f ? cs : 0.f;
            float att = __expf(-sig);
            float uu  = miu * att;
            float vv  = sig * att * att;
            unsigned int p = (unsigned int)f2bf(uu) | ((unsigned int)f2bf(vv) << 16);
            uv[(size_t)m * OUTF + f] = p;
        }
    }
}

// ---------------------------------------------------------------------------
// K2a: per-chunk sums of cnt.
// ---------------------------------------------------------------------------
__global__ __launch_bounds__(256) void chunk_sum(
    const int* __restrict__ cnt, int* __restrict__ chunkSum)
{
    __shared__ int buf[256];
    const int t   = threadIdx.x;
    const int idx = blockIdx.x * 256 + t;
    buf[t] = (idx < NNODES) ? cnt[idx] : 0;
    __syncthreads();
    #pragma unroll
    for (int off = 128; off > 0; off >>= 1) {
        if (t < off) buf[t] += buf[t + off];
        __syncthreads();
    }
    if (t == 0) chunkSum[blockIdx.x] = buf[0];
}

// ---------------------------------------------------------------------------
// K2b: per-chunk exclusive scan + write start/cursor.
// ---------------------------------------------------------------------------
__global__ __launch_bounds__(256) void scan_write(
    const int* __restrict__ cnt, const int* __restrict__ chunkSum,
    int* __restrict__ start, int* __restrict__ cursor)
{
    __shared__ int pre[256];
    __shared__ int buf[256];
    const int t   = threadIdx.x;
    const int b   = blockIdx.x;
    const int idx = b * 256 + t;

    pre[t] = (t < NCHUNK && t < b) ? chunkSum[t] : 0;
    int val = (idx < NNODES) ? cnt[idx] : 0;
    buf[t] = val;
    __syncthreads();

    #pragma unroll
    for (int off = 128; off > 0; off >>= 1) {
        if (t < off) pre[t] += pre[t + off];
        __syncthreads();
    }
    const int chunkOff = pre[0];

    #pragma unroll
    for (int off = 1; off < 256; off <<= 1) {
        int x = (t >= off) ? buf[t - off] : 0;
        __syncthreads();
        buf[t] += x;
        __syncthreads();
    }
    if (idx < NNODES) {
        int excl = chunkOff + buf[t] - val;
        start[idx]  = excl;
        cursor[idx] = excl;
    }
    if (b == NCHUNK - 1 && t == 255) start[NNODES] = NEDGES;
}

// ---------------------------------------------------------------------------
// K3: place SORTED TUPLES (src, a1, a2, pad) into per-dst segments.
// All reads coalesced; one scattered 16B write per edge.
// ---------------------------------------------------------------------------
__global__ __launch_bounds__(256) void place_kernel(
    const int* __restrict__ esrc,
    const int* __restrict__ edst,
    const float* __restrict__ a1,
    const float* __restrict__ a2,
    int* __restrict__ cursor,
    int4* __restrict__ tup)
{
    int e = blockIdx.x * 256 + threadIdx.x;
    if (e < NEDGES) {
        int pos = atomicAdd(&cursor[edst[e]], 1);
        tup[pos] = make_int4(esrc[e], __float_as_int(a1[e]),
                             __float_as_int(a2[e]), 0);
    }
}

// ---------------------------------------------------------------------------
// K4: one wave per dst node; lane = feature. Metadata streamed from sorted
// tuples (sequential); only uv gather is random. 8-edge unroll -> 8
// independent 2-level chains in flight.
// ---------------------------------------------------------------------------
__global__ __launch_bounds__(256) void gather_accum(
    const int4* __restrict__ tup,
    const int* __restrict__ start,
    const unsigned int* __restrict__ uv,
    float* __restrict__ outm,
    float* __restrict__ outs)
{
    const int n    = blockIdx.x * 4 + (threadIdx.x >> 6);
    const int lane = threadIdx.x & 63;
    if (n >= NNODES) return;

    const int beg = start[n];
    const int end = start[n + 1];

    float am = 0.f, as = 0.f;
    int i = beg;
    for (; i + 8 <= end; i += 8) {
        #pragma unroll
        for (int j = 0; j < 8; ++j) {
            int4 t = tup[i + j];
            unsigned int p = uv[(size_t)t.x * OUTF + lane];
            am = fmaf(__int_as_float(t.y), __uint_as_float(p << 16), am);
            as = fmaf(__int_as_float(t.z), __uint_as_float(p & 0xFFFF0000u), as);
        }
    }
    for (; i < end; ++i) {
        int4 t = tup[i];
        unsigned int p = uv[(size_t)t.x * OUTF + lane];
        am = fmaf(__int_as_float(t.y), __uint_as_float(p << 16), am);
        as = fmaf(__int_as_float(t.z), __uint_as_float(p & 0xFFFF0000u), as);
    }

    outm[(size_t)n * OUTF + lane] = am;
    outs[(size_t)n * OUTF + lane] = as;
}

extern "C" void kernel_launch(void* const* d_in, const int* in_sizes, int n_in,
                              void* d_out, int out_size, void* d_ws, size_t ws_size,
                              hipStream_t stream)
{
    const float* feat = (const float*)d_in[0];
    const int*   esrc = (const int*)d_in[1];
    const int*   edst = (const int*)d_in[2];
    const float* a1   = (const float*)d_in[3];
    const float* a2   = (const float*)d_in[4];
    const float* Wm   = (const float*)d_in[5];
    const float* Ws   = (const float*)d_in[6];

    float* outm = (float*)d_out;
    float* outs = outm + (size_t)NNODES * OUTF;

    // workspace layout (~26.4 MB)
    char* ws = (char*)d_ws;
    unsigned int*   uv  = (unsigned int*)ws;   ws += (size_t)NNODES * OUTF * 4;  // 12.8 MB
    unsigned short* BtG = (unsigned short*)ws; ws += (size_t)128 * INF * 2;      // 64 KB
    int4* tup     = (int4*)ws; ws += (size_t)NEDGES * 16;                         // 12.8 MB
    int* cnt      = (int*)ws;  ws += (size_t)NNODES * 4;
    int* start    = (int*)ws;  ws += (size_t)(NNODES + 1) * 4;
    int* cursor   = (int*)ws;  ws += (size_t)NNODES * 4;
    int* chunkSum = (int*)ws;

    hipMemsetAsync(cnt, 0, (size_t)NNODES * sizeof(int), stream);

    convert_hist<<<dim3(CVTBLK + (NEDGES + 255) / 256), dim3(256), 0, stream>>>(
        Wm, Ws, BtG, edst, cnt);

    gemm_mfma<<<dim3((NNODES + 63) / 64), dim3(256), 0, stream>>>(
        feat, BtG, uv, NNODES);

    chunk_sum<<<dim3(NCHUNK), dim3(256), 0, stream>>>(cnt, chunkSum);
    scan_write<<<dim3(NCHUNK), dim3(256), 0, stream>>>(cnt, chunkSum, start, cursor);
    place_kernel<<<dim3((NEDGES + 255) / 256), dim3(256), 0, stream>>>(
        esrc, edst, a1, a2, cursor, tup);
    gather_accum<<<dim3((NNODES + 3) / 4), dim3(256), 0, stream>>>(
        tup, start, uv, outm, outs);
}

// Round 7
// 250.584 us; speedup vs baseline: 4.1704x; 1.0474x over previous
//
#include <hip/hip_runtime.h>
#include <math.h>

#define NNODES 50000
#define INF    256
#define OUTF   64
#define NEDGES 800000
#define NCHUNK 196            // ceil(50000/256)
#define CVTBLK 128            // blocks doing weight conversion in fused K1
#define HISTBLK ((NEDGES + 1023) / 1024)   // 782: 1024 edges/block, 4/thread
#define PLACEBLK ((NEDGES + 1023) / 1024)  // 782

typedef __attribute__((ext_vector_type(8))) short bf16x8;
typedef __attribute__((ext_vector_type(4))) float f32x4;

__device__ __forceinline__ unsigned short f2bf(float x) {
    unsigned int b = __float_as_uint(x);
    unsigned int r = b + 0x7FFF + ((b >> 16) & 1);   // RNE
    return (unsigned short)(r >> 16);
}

// ---------------------------------------------------------------------------
// K1 (fused): blocks 0..127 transpose+convert weights; blocks 128.. histogram
// with 4 edges/thread for ILP.
// ---------------------------------------------------------------------------
__global__ __launch_bounds__(256) void convert_hist(
    const float* __restrict__ Wm, const float* __restrict__ Ws,
    unsigned short* __restrict__ BtG,
    const int* __restrict__ edst, int* __restrict__ cnt)
{
    if (blockIdx.x < CVTBLK) {
        int n = blockIdx.x;          // 0..127
        int k = threadIdx.x;         // 0..255
        float val = (n < 64) ? Wm[(size_t)k * OUTF + n]
                             : Ws[(size_t)k * OUTF + (n - 64)];
        BtG[(size_t)n * INF + k] = f2bf(val);
    } else {
        int base = (blockIdx.x - CVTBLK) * 1024 + threadIdx.x;
        int d[4];
        #pragma unroll
        for (int j = 0; j < 4; ++j) {
            int e = base + j * 256;
            d[j] = (e < NEDGES) ? edst[e] : -1;
        }
        #pragma unroll
        for (int j = 0; j < 4; ++j)
            if (d[j] >= 0) atomicAdd(&cnt[d[j]], 1);
    }
}

// ---------------------------------------------------------------------------
// K-GEMM: bf16 MFMA fused dual-GEMM + activation epilogue.
// ---------------------------------------------------------------------------
#define LDA 40   // padded k-stride (bf16 elems)
__global__ __launch_bounds__(256, 2) void gemm_mfma(
    const float* __restrict__ feat,
    const unsigned short* __restrict__ BtG,
    unsigned int* __restrict__ uv,
    int n_nodes)
{
    __shared__ __align__(16) unsigned short As[64 * LDA];
    __shared__ __align__(16) unsigned short Bs[128 * LDA];

    const int tid  = threadIdx.x;
    const int w    = tid >> 6;
    const int lane = tid & 63;
    const int quad = lane >> 4;
    const int col  = lane & 15;
    const int m0   = blockIdx.x * 64;

    f32x4 acc[8];
    #pragma unroll
    for (int c = 0; c < 8; ++c) acc[c] = (f32x4){0.f, 0.f, 0.f, 0.f};

    for (int kb = 0; kb < INF; kb += 32) {
        #pragma unroll
        for (int r = 0; r < 2; ++r) {
            int i   = tid + r * 256;
            int row = i >> 3;
            int q4  = i & 7;
            int m   = m0 + row;
            float4 val = make_float4(0.f, 0.f, 0.f, 0.f);
            if (m < n_nodes)
                val = *(const float4*)&feat[(size_t)m * INF + kb + q4 * 4];
            unsigned short p0 = f2bf(val.x), p1 = f2bf(val.y);
            unsigned short p2 = f2bf(val.z), p3 = f2bf(val.w);
            unsigned int lo = (unsigned int)p0 | ((unsigned int)p1 << 16);
            unsigned int hi = (unsigned int)p2 | ((unsigned int)p3 << 16);
            *(uint2*)&As[row * LDA + q4 * 4] = make_uint2(lo, hi);
        }
        #pragma unroll
        for (int r = 0; r < 2; ++r) {
            int i = tid + r * 256;
            int n = i >> 2;
            int q = i & 3;
            uint4 val = *(const uint4*)&BtG[(size_t)n * INF + kb + q * 8];
            *(uint4*)&Bs[n * LDA + q * 8] = val;
        }
        __syncthreads();

        bf16x8 af = *(const bf16x8*)&As[(16 * w + col) * LDA + quad * 8];
        #pragma unroll
        for (int c = 0; c < 8; ++c) {
            bf16x8 bf = *(const bf16x8*)&Bs[(16 * c + col) * LDA + quad * 8];
            acc[c] = __builtin_amdgcn_mfma_f32_16x16x32_bf16(af, bf, acc[c], 0, 0, 0);
        }
        __syncthreads();
    }

    const int mbase = m0 + 16 * w + quad * 4;
    #pragma unroll
    for (int c = 0; c < 4; ++c) {
        int f = 16 * c + col;
        #pragma unroll
        for (int r = 0; r < 4; ++r) {
            int m = mbase + r;
            if (m >= n_nodes) continue;
            float cm  = acc[c][r];
            float cs  = acc[c + 4][r];
            float miu = cm > 0.f ? cm : expm1f(cm);
            float sig = cs > 0.f ? cs : 0.f;
            float att = __expf(-sig);
            float uu  = miu * att;
            float vv  = sig * att * att;
            unsigned int p = (unsigned int)f2bf(uu) | ((unsigned int)f2bf(vv) << 16);
            uv[(size_t)m * OUTF + f] = p;
        }
    }
}

// ---------------------------------------------------------------------------
// K2a: per-chunk sums of cnt.
// ---------------------------------------------------------------------------
__global__ __launch_bounds__(256) void chunk_sum(
    const int* __restrict__ cnt, int* __restrict__ chunkSum)
{
    __shared__ int buf[256];
    const int t   = threadIdx.x;
    const int idx = blockIdx.x * 256 + t;
    buf[t] = (idx < NNODES) ? cnt[idx] : 0;
    __syncthreads();
    #pragma unroll
    for (int off = 128; off > 0; off >>= 1) {
        if (t < off) buf[t] += buf[t + off];
        __syncthreads();
    }
    if (t == 0) chunkSum[blockIdx.x] = buf[0];
}

// ---------------------------------------------------------------------------
// K2b: per-chunk exclusive scan + write start/cursor.
// ---------------------------------------------------------------------------
__global__ __launch_bounds__(256) void scan_write(
    const int* __restrict__ cnt, const int* __restrict__ chunkSum,
    int* __restrict__ start, int* __restrict__ cursor)
{
    __shared__ int pre[256];
    __shared__ int buf[256];
    const int t   = threadIdx.x;
    const int b   = blockIdx.x;
    const int idx = b * 256 + t;

    pre[t] = (t < NCHUNK && t < b) ? chunkSum[t] : 0;
    int val = (idx < NNODES) ? cnt[idx] : 0;
    buf[t] = val;
    __syncthreads();

    #pragma unroll
    for (int off = 128; off > 0; off >>= 1) {
        if (t < off) pre[t] += pre[t + off];
        __syncthreads();
    }
    const int chunkOff = pre[0];

    #pragma unroll
    for (int off = 1; off < 256; off <<= 1) {
        int x = (t >= off) ? buf[t - off] : 0;
        __syncthreads();
        buf[t] += x;
        __syncthreads();
    }
    if (idx < NNODES) {
        int excl = chunkOff + buf[t] - val;
        start[idx]  = excl;
        cursor[idx] = excl;
    }
    if (b == NCHUNK - 1 && t == 255) start[NNODES] = NEDGES;
}

// ---------------------------------------------------------------------------
// K3: place sorted tuples (src, a1, a2, pad), 4 edges/thread for ILP.
// 4 independent chains: edst load -> returning atomic -> 16B scattered write.
// ---------------------------------------------------------------------------
__global__ __launch_bounds__(256) void place_kernel(
    const int* __restrict__ esrc,
    const int* __restrict__ edst,
    const float* __restrict__ a1,
    const float* __restrict__ a2,
    int* __restrict__ cursor,
    int4* __restrict__ tup)
{
    const int base = blockIdx.x * 1024 + threadIdx.x;

    int   d[4], s[4];
    float w1[4], w2[4];
    bool  ok[4];
    #pragma unroll
    for (int j = 0; j < 4; ++j) {
        int e = base + j * 256;
        ok[j] = (e < NEDGES);
        int ec = ok[j] ? e : 0;
        d[j]  = edst[ec];
        s[j]  = esrc[ec];
        w1[j] = a1[ec];
        w2[j] = a2[ec];
    }
    int pos[4];
    #pragma unroll
    for (int j = 0; j < 4; ++j)
        pos[j] = ok[j] ? atomicAdd(&cursor[d[j]], 1) : 0;
    #pragma unroll
    for (int j = 0; j < 4; ++j)
        if (ok[j])
            tup[pos[j]] = make_int4(s[j], __float_as_int(w1[j]),
                                    __float_as_int(w2[j]), 0);
}

// ---------------------------------------------------------------------------
// K4: one wave per dst node; lane = feature. Metadata streamed (sorted
// tuples), only uv gather random; 8-edge unroll.
// ---------------------------------------------------------------------------
__global__ __launch_bounds__(256) void gather_accum(
    const int4* __restrict__ tup,
    const int* __restrict__ start,
    const unsigned int* __restrict__ uv,
    float* __restrict__ outm,
    float* __restrict__ outs)
{
    const int n    = blockIdx.x * 4 + (threadIdx.x >> 6);
    const int lane = threadIdx.x & 63;
    if (n >= NNODES) return;

    const int beg = start[n];
    const int end = start[n + 1];

    float am = 0.f, as = 0.f;
    int i = beg;
    for (; i + 8 <= end; i += 8) {
        #pragma unroll
        for (int j = 0; j < 8; ++j) {
            int4 t = tup[i + j];
            unsigned int p = uv[(size_t)t.x * OUTF + lane];
            am = fmaf(__int_as_float(t.y), __uint_as_float(p << 16), am);
            as = fmaf(__int_as_float(t.z), __uint_as_float(p & 0xFFFF0000u), as);
        }
    }
    for (; i < end; ++i) {
        int4 t = tup[i];
        unsigned int p = uv[(size_t)t.x * OUTF + lane];
        am = fmaf(__int_as_float(t.y), __uint_as_float(p << 16), am);
        as = fmaf(__int_as_float(t.z), __uint_as_float(p & 0xFFFF0000u), as);
    }

    outm[(size_t)n * OUTF + lane] = am;
    outs[(size_t)n * OUTF + lane] = as;
}

extern "C" void kernel_launch(void* const* d_in, const int* in_sizes, int n_in,
                              void* d_out, int out_size, void* d_ws, size_t ws_size,
                              hipStream_t stream)
{
    const float* feat = (const float*)d_in[0];
    const int*   esrc = (const int*)d_in[1];
    const int*   edst = (const int*)d_in[2];
    const float* a1   = (const float*)d_in[3];
    const float* a2   = (const float*)d_in[4];
    const float* Wm   = (const float*)d_in[5];
    const float* Ws   = (const float*)d_in[6];

    float* outm = (float*)d_out;
    float* outs = outm + (size_t)NNODES * OUTF;

    // workspace layout (~26.4 MB)
    char* ws = (char*)d_ws;
    unsigned int*   uv  = (unsigned int*)ws;   ws += (size_t)NNODES * OUTF * 4;  // 12.8 MB
    unsigned short* BtG = (unsigned short*)ws; ws += (size_t)128 * INF * 2;      // 64 KB
    int4* tup     = (int4*)ws; ws += (size_t)NEDGES * 16;                         // 12.8 MB
    int* cnt      = (int*)ws;  ws += (size_t)NNODES * 4;
    int* start    = (int*)ws;  ws += (size_t)(NNODES + 1) * 4;
    int* cursor   = (int*)ws;  ws += (size_t)NNODES * 4;
    int* chunkSum = (int*)ws;

    hipMemsetAsync(cnt, 0, (size_t)NNODES * sizeof(int), stream);

    convert_hist<<<dim3(CVTBLK + HISTBLK), dim3(256), 0, stream>>>(
        Wm, Ws, BtG, edst, cnt);

    gemm_mfma<<<dim3((NNODES + 63) / 64), dim3(256), 0, stream>>>(
        feat, BtG, uv, NNODES);

    chunk_sum<<<dim3(NCHUNK), dim3(256), 0, stream>>>(cnt, chunkSum);
    scan_write<<<dim3(NCHUNK), dim3(256), 0, stream>>>(cnt, chunkSum, start, cursor);
    place_kernel<<<dim3(PLACEBLK), dim3(256), 0, stream>>>(
        esrc, edst, a1, a2, cursor, tup);
    gather_accum<<<dim3((NNODES + 3) / 4), dim3(256), 0, stream>>>(
        tup, start, uv, outm, outs);
}

// Round 8
// 233.144 us; speedup vs baseline: 4.4824x; 1.0748x over previous
//
#include <hip/hip_runtime.h>
#include <math.h>

#define NNODES 50000
#define INF    256
#define OUTF   64
#define NEDGES 800000
#define NCHUNK 196            // ceil(50000/256)
#define CVTBLK 128            // blocks doing weight conversion in fused K1
#define HISTBLK ((NEDGES + 1023) / 1024)   // 782: 1024 edges/block, 4/thread
#define CSTRIDE 16            // one counter per 64B cacheline

typedef __attribute__((ext_vector_type(8))) short bf16x8;
typedef __attribute__((ext_vector_type(4))) float f32x4;

__device__ __forceinline__ unsigned short f2bf(float x) {
    unsigned int b = __float_as_uint(x);
    unsigned int r = b + 0x7FFF + ((b >> 16) & 1);   // RNE
    return (unsigned short)(r >> 16);
}

// ---------------------------------------------------------------------------
// K1 (fused): blocks 0..127 transpose+convert weights; blocks 128..: dst
// histogram with line-strided counters, capturing each edge's RANK (return
// value of the atomic). 4 edges/thread for ILP.
// ---------------------------------------------------------------------------
__global__ __launch_bounds__(256) void convert_hist(
    const float* __restrict__ Wm, const float* __restrict__ Ws,
    unsigned short* __restrict__ BtG,
    const int* __restrict__ edst, int* __restrict__ cntS,
    int* __restrict__ rank)
{
    if (blockIdx.x < CVTBLK) {
        int n = blockIdx.x;          // 0..127
        int k = threadIdx.x;         // 0..255
        float val = (n < 64) ? Wm[(size_t)k * OUTF + n]
                             : Ws[(size_t)k * OUTF + (n - 64)];
        BtG[(size_t)n * INF + k] = f2bf(val);
    } else {
        int base = (blockIdx.x - CVTBLK) * 1024 + threadIdx.x;
        int d[4];
        bool ok[4];
        #pragma unroll
        for (int j = 0; j < 4; ++j) {
            int e = base + j * 256;
            ok[j] = (e < NEDGES);
            d[j]  = ok[j] ? edst[e] : 0;
        }
        int r[4];
        #pragma unroll
        for (int j = 0; j < 4; ++j)
            r[j] = ok[j] ? atomicAdd(&cntS[(size_t)d[j] * CSTRIDE], 1) : 0;
        #pragma unroll
        for (int j = 0; j < 4; ++j)
            if (ok[j]) rank[base + j * 256] = r[j];
    }
}

// ---------------------------------------------------------------------------
// K-GEMM: bf16 MFMA fused dual-GEMM + activation epilogue.
// ---------------------------------------------------------------------------
#define LDA 40   // padded k-stride (bf16 elems)
__global__ __launch_bounds__(256, 2) void gemm_mfma(
    const float* __restrict__ feat,
    const unsigned short* __restrict__ BtG,
    unsigned int* __restrict__ uv,
    int n_nodes)
{
    __shared__ __align__(16) unsigned short As[64 * LDA];
    __shared__ __align__(16) unsigned short Bs[128 * LDA];

    const int tid  = threadIdx.x;
    const int w    = tid >> 6;
    const int lane = tid & 63;
    const int quad = lane >> 4;
    const int col  = lane & 15;
    const int m0   = blockIdx.x * 64;

    f32x4 acc[8];
    #pragma unroll
    for (int c = 0; c < 8; ++c) acc[c] = (f32x4){0.f, 0.f, 0.f, 0.f};

    for (int kb = 0; kb < INF; kb += 32) {
        #pragma unroll
        for (int r = 0; r < 2; ++r) {
            int i   = tid + r * 256;
            int row = i >> 3;
            int q4  = i & 7;
            int m   = m0 + row;
            float4 val = make_float4(0.f, 0.f, 0.f, 0.f);
            if (m < n_nodes)
                val = *(const float4*)&feat[(size_t)m * INF + kb + q4 * 4];
            unsigned short p0 = f2bf(val.x), p1 = f2bf(val.y);
            unsigned short p2 = f2bf(val.z), p3 = f2bf(val.w);
            unsigned int lo = (unsigned int)p0 | ((unsigned int)p1 << 16);
            unsigned int hi = (unsigned int)p2 | ((unsigned int)p3 << 16);
            *(uint2*)&As[row * LDA + q4 * 4] = make_uint2(lo, hi);
        }
        #pragma unroll
        for (int r = 0; r < 2; ++r) {
            int i = tid + r * 256;
            int n = i >> 2;
            int q = i & 3;
            uint4 val = *(const uint4*)&BtG[(size_t)n * INF + kb + q * 8];
            *(uint4*)&Bs[n * LDA + q * 8] = val;
        }
        __syncthreads();

        bf16x8 af = *(const bf16x8*)&As[(16 * w + col) * LDA + quad * 8];
        #pragma unroll
        for (int c = 0; c < 8; ++c) {
            bf16x8 bf = *(const bf16x8*)&Bs[(16 * c + col) * LDA + quad * 8];
            acc[c] = __builtin_amdgcn_mfma_f32_16x16x32_bf16(af, bf, acc[c], 0, 0, 0);
        }
        __syncthreads();
    }

    const int mbase = m0 + 16 * w + quad * 4;
    #pragma unroll
    for (int c = 0; c < 4; ++c) {
        int f = 16 * c + col;
        #pragma unroll
        for (int r = 0; r < 4; ++r) {
            int m = mbase + r;
            if (m >= n_nodes) continue;
            float cm  = acc[c][r];
            float cs  = acc[c + 4][r];
            float miu = cm > 0.f ? cm : expm1f(cm);
            float sig = cs > 0.f ? cs : 0.f;
            float att = __expf(-sig);
            float uu  = miu * att;
            float vv  = sig * att * att;
            unsigned int p = (unsigned int)f2bf(uu) | ((unsigned int)f2bf(vv) << 16);
            uv[(size_t)m * OUTF + f] = p;
        }
    }
}

// ---------------------------------------------------------------------------
// K2a: per-chunk sums over line-strided cnt.
// ---------------------------------------------------------------------------
__global__ __launch_bounds__(256) void chunk_sum(
    const int* __restrict__ cntS, int* __restrict__ chunkSum)
{
    __shared__ int buf[256];
    const int t   = threadIdx.x;
    const int idx = blockIdx.x * 256 + t;
    buf[t] = (idx < NNODES) ? cntS[(size_t)idx * CSTRIDE] : 0;
    __syncthreads();
    #pragma unroll
    for (int off = 128; off > 0; off >>= 1) {
        if (t < off) buf[t] += buf[t + off];
        __syncthreads();
    }
    if (t == 0) chunkSum[blockIdx.x] = buf[0];
}

// ---------------------------------------------------------------------------
// K2b: per-chunk exclusive scan + write start.
// ---------------------------------------------------------------------------
__global__ __launch_bounds__(256) void scan_write(
    const int* __restrict__ cntS, const int* __restrict__ chunkSum,
    int* __restrict__ start)
{
    __shared__ int pre[256];
    __shared__ int buf[256];
    const int t   = threadIdx.x;
    const int b   = blockIdx.x;
    const int idx = b * 256 + t;

    pre[t] = (t < NCHUNK && t < b) ? chunkSum[t] : 0;
    int val = (idx < NNODES) ? cntS[(size_t)idx * CSTRIDE] : 0;
    buf[t] = val;
    __syncthreads();

    #pragma unroll
    for (int off = 128; off > 0; off >>= 1) {
        if (t < off) pre[t] += pre[t + off];
        __syncthreads();
    }
    const int chunkOff = pre[0];

    #pragma unroll
    for (int off = 1; off < 256; off <<= 1) {
        int x = (t >= off) ? buf[t - off] : 0;
        __syncthreads();
        buf[t] += x;
        __syncthreads();
    }
    if (idx < NNODES)
        start[idx] = chunkOff + buf[t] - val;
    if (b == NCHUNK - 1 && t == 255) start[NNODES] = NEDGES;
}

// ---------------------------------------------------------------------------
// K3: place sorted tuples — NO ATOMICS. pos = start[dst] + rank[e].
// All reads coalesced except start[dst] (200 KB, L2-served).
// ---------------------------------------------------------------------------
__global__ __launch_bounds__(256) void place_kernel(
    const int* __restrict__ esrc,
    const int* __restrict__ edst,
    const float* __restrict__ a1,
    const float* __restrict__ a2,
    const int* __restrict__ rank,
    const int* __restrict__ start,
    int4* __restrict__ tup)
{
    const int base = blockIdx.x * 1024 + threadIdx.x;

    #pragma unroll
    for (int j = 0; j < 4; ++j) {
        int e = base + j * 256;
        if (e < NEDGES) {
            int d   = edst[e];
            int pos = start[d] + rank[e];
            tup[pos] = make_int4(esrc[e], __float_as_int(a1[e]),
                                 __float_as_int(a2[e]), 0);
        }
    }
}

// ---------------------------------------------------------------------------
// K4: one wave per dst node; lane = feature. Metadata streamed (sorted
// tuples), only uv gather random; 8-edge unroll.
// ---------------------------------------------------------------------------
__global__ __launch_bounds__(256) void gather_accum(
    const int4* __restrict__ tup,
    const int* __restrict__ start,
    const unsigned int* __restrict__ uv,
    float* __restrict__ outm,
    float* __restrict__ outs)
{
    const int n    = blockIdx.x * 4 + (threadIdx.x >> 6);
    const int lane = threadIdx.x & 63;
    if (n >= NNODES) return;

    const int beg = start[n];
    const int end = start[n + 1];

    float am = 0.f, as = 0.f;
    int i = beg;
    for (; i + 8 <= end; i += 8) {
        #pragma unroll
        for (int j = 0; j < 8; ++j) {
            int4 t = tup[i + j];
            unsigned int p = uv[(size_t)t.x * OUTF + lane];
            am = fmaf(__int_as_float(t.y), __uint_as_float(p << 16), am);
            as = fmaf(__int_as_float(t.z), __uint_as_float(p & 0xFFFF0000u), as);
        }
    }
    for (; i < end; ++i) {
        int4 t = tup[i];
        unsigned int p = uv[(size_t)t.x * OUTF + lane];
        am = fmaf(__int_as_float(t.y), __uint_as_float(p << 16), am);
        as = fmaf(__int_as_float(t.z), __uint_as_float(p & 0xFFFF0000u), as);
    }

    outm[(size_t)n * OUTF + lane] = am;
    outs[(size_t)n * OUTF + lane] = as;
}

extern "C" void kernel_launch(void* const* d_in, const int* in_sizes, int n_in,
                              void* d_out, int out_size, void* d_ws, size_t ws_size,
                              hipStream_t stream)
{
    const float* feat = (const float*)d_in[0];
    const int*   esrc = (const int*)d_in[1];
    const int*   edst = (const int*)d_in[2];
    const float* a1   = (const float*)d_in[3];
    const float* a2   = (const float*)d_in[4];
    const float* Wm   = (const float*)d_in[5];
    const float* Ws   = (const float*)d_in[6];

    float* outm = (float*)d_out;
    float* outs = outm + (size_t)NNODES * OUTF;

    // workspace layout (~33 MB)
    char* ws = (char*)d_ws;
    unsigned int*   uv  = (unsigned int*)ws;   ws += (size_t)NNODES * OUTF * 4;   // 12.8 MB
    unsigned short* BtG = (unsigned short*)ws; ws += (size_t)128 * INF * 2;       // 64 KB
    int4* tup     = (int4*)ws; ws += (size_t)NEDGES * 16;                          // 12.8 MB
    int* rank     = (int*)ws;  ws += (size_t)NEDGES * 4;                           // 3.2 MB
    int* cntS     = (int*)ws;  ws += (size_t)NNODES * CSTRIDE * 4;                 // 3.2 MB
    int* start    = (int*)ws;  ws += (size_t)(NNODES + 1) * 4;
    int* chunkSum = (int*)ws;

    hipMemsetAsync(cntS, 0, (size_t)NNODES * CSTRIDE * sizeof(int), stream);

    convert_hist<<<dim3(CVTBLK + HISTBLK), dim3(256), 0, stream>>>(
        Wm, Ws, BtG, edst, cntS, rank);

    gemm_mfma<<<dim3((NNODES + 63) / 64), dim3(256), 0, stream>>>(
        feat, BtG, uv, NNODES);

    chunk_sum<<<dim3(NCHUNK), dim3(256), 0, stream>>>(cntS, chunkSum);
    scan_write<<<dim3(NCHUNK), dim3(256), 0, stream>>>(cntS, chunkSum, start);
    place_kernel<<<dim3(HISTBLK), dim3(256), 0, stream>>>(
        esrc, edst, a1, a2, rank, start, tup);
    gather_accum<<<dim3((NNODES + 3) / 4), dim3(256), 0, stream>>>(
        tup, start, uv, outm, outs);
}